// Round 1
// baseline (105.509 us; speedup 1.0000x reference)
//
#include <hip/hip_runtime.h>

// Problem constants (match reference)
#define BATCH 4096
#define VOCAB 30000
#define SETSZ 64
#define LAMBDA_REG 10.0f

// ---------------------------------------------------------------------------
// Kernel 1: per-row streaming reduction over pred.
//   sumsq[i]  = sum_v pred[i,v]^2
//   expsum[i] = sum_v exp(pred[i,v])
// One block (256 threads) per row; float4 vector loads (30000 % 4 == 0,
// row byte offset 120000 is 16B-aligned).
// ---------------------------------------------------------------------------
__global__ __launch_bounds__(256) void row_reduce_kernel(
    const float* __restrict__ pred,
    float* __restrict__ sumsq,
    float* __restrict__ expsum) {
  const int row = blockIdx.x;
  const float4* p = reinterpret_cast<const float4*>(pred + (size_t)row * VOCAB);

  float ss = 0.f, es = 0.f;
  for (int j = threadIdx.x; j < VOCAB / 4; j += 256) {
    float4 v = p[j];
    ss += v.x * v.x + v.y * v.y + v.z * v.z + v.w * v.w;
    es += __expf(v.x) + __expf(v.y) + __expf(v.z) + __expf(v.w);
  }

  // wave64 butterfly reduce
  #pragma unroll
  for (int off = 32; off > 0; off >>= 1) {
    ss += __shfl_down(ss, off, 64);
    es += __shfl_down(es, off, 64);
  }

  __shared__ float s_ss[4], s_es[4];
  const int wave = threadIdx.x >> 6;
  const int lane = threadIdx.x & 63;
  if (lane == 0) { s_ss[wave] = ss; s_es[wave] = es; }
  __syncthreads();
  if (threadIdx.x == 0) {
    sumsq[row]  = s_ss[0] + s_ss[1] + s_ss[2] + s_ss[3];
    expsum[row] = s_es[0] + s_es[1] + s_es[2] + s_es[3];
  }
}

// ---------------------------------------------------------------------------
// Kernel 2: per-row target handling (one wave per row).
//   - dedupe the 64 targets (scatter .set(1.0) is idempotent on duplicates)
//   - gather pred at distinct target indices
//   - mse_i  = w_i * (sumsq_i + sum_pos (1 - 2 p))
//   - set_i  = (sum_pos exp(-p)) * (expsum_i - sum_pos exp(p)) / (n_pos*n_neg)
//   - row_loss[i] = (mse_i + LAMBDA * set_i) / BATCH
// ---------------------------------------------------------------------------
__global__ __launch_bounds__(64) void row_loss_kernel(
    const float* __restrict__ pred,
    const int* __restrict__ target,
    const float* __restrict__ weights,
    const float* __restrict__ sumsq,
    const float* __restrict__ expsum,
    float* __restrict__ row_loss) {
  const int row = blockIdx.x;
  const int t = threadIdx.x;

  __shared__ int tg[SETSZ];
  const int my = target[row * SETSZ + t];
  tg[t] = my;
  __syncthreads();

  // keep only the first occurrence of each index
  bool keep = true;
  for (int k = 0; k < t; ++k) {
    if (tg[k] == my) { keep = false; break; }
  }

  float c_mse = 0.f, c_pos = 0.f, c_exp = 0.f, cnt = 0.f;
  if (keep) {
    const float p = pred[(size_t)row * VOCAB + my];
    c_mse = 1.f - 2.f * p;   // (p-1)^2 - p^2
    c_pos = __expf(-p);
    c_exp = __expf(p);
    cnt = 1.f;
  }

  #pragma unroll
  for (int off = 32; off > 0; off >>= 1) {
    c_mse += __shfl_down(c_mse, off, 64);
    c_pos += __shfl_down(c_pos, off, 64);
    c_exp += __shfl_down(c_exp, off, 64);
    cnt   += __shfl_down(cnt,   off, 64);
  }

  if (t == 0) {
    const float n_pos = cnt;
    const float n_neg = (float)VOCAB - n_pos;
    const float mse   = weights[row] * (sumsq[row] + c_mse);
    const float setl  = c_pos * (expsum[row] - c_exp) / (n_pos * n_neg);
    row_loss[row] = (mse + LAMBDA_REG * setl) * (1.0f / (float)BATCH);
  }
}

// ---------------------------------------------------------------------------
// Kernel 3: deterministic final reduction of 4096 row losses -> d_out[0].
// Single block, fixed tree order -> bit-identical across replays.
// ---------------------------------------------------------------------------
__global__ __launch_bounds__(256) void final_reduce_kernel(
    const float* __restrict__ row_loss,
    float* __restrict__ out) {
  float s = 0.f;
  for (int j = threadIdx.x; j < BATCH; j += 256) s += row_loss[j];

  #pragma unroll
  for (int off = 32; off > 0; off >>= 1) s += __shfl_down(s, off, 64);

  __shared__ float sm[4];
  const int wave = threadIdx.x >> 6;
  const int lane = threadIdx.x & 63;
  if (lane == 0) sm[wave] = s;
  __syncthreads();
  if (threadIdx.x == 0) out[0] = sm[0] + sm[1] + sm[2] + sm[3];
}

extern "C" void kernel_launch(void* const* d_in, const int* in_sizes, int n_in,
                              void* d_out, int out_size, void* d_ws, size_t ws_size,
                              hipStream_t stream) {
  const float* pred    = (const float*)d_in[0];
  const int*   target  = (const int*)d_in[1];
  const float* weights = (const float*)d_in[2];
  float* out = (float*)d_out;

  // workspace layout: sumsq[BATCH] | expsum[BATCH] | row_loss[BATCH]
  float* sumsq    = (float*)d_ws;
  float* expsum   = sumsq + BATCH;
  float* row_loss = expsum + BATCH;

  row_reduce_kernel<<<BATCH, 256, 0, stream>>>(pred, sumsq, expsum);
  row_loss_kernel<<<BATCH, 64, 0, stream>>>(pred, target, weights, sumsq, expsum, row_loss);
  final_reduce_kernel<<<1, 256, 0, stream>>>(row_loss, out);
}

// Round 2
// 93.183 us; speedup vs baseline: 1.1323x; 1.1323x over previous
//
#include <hip/hip_runtime.h>

// Problem constants (match reference)
#define BATCH 4096
#define VOCAB 30000
#define SETSZ 64
#define LAMBDA_REG 10.0f

typedef float f4 __attribute__((ext_vector_type(4)));

// ---------------------------------------------------------------------------
// Fused kernel: one block (256 threads) per row.
//   Phase 1 (all 4 waves): stream the row with nontemporal float4 loads,
//     accumulating sumsq = sum p^2 and expsum = sum exp(p).
//   Phase 2 (wave 0 only): dedupe the 64 targets (scatter is idempotent),
//     gather pred at distinct targets (L1/L2-hot from phase 1... nt loads
//     bypass, but it's 64 loads/row, fully latency-hidden across blocks),
//     and combine into the per-row loss:
//       mse_i  = w_i * (sumsq + sum_pos (1 - 2 p))
//       set_i  = (sum_pos exp(-p)) * (expsum - sum_pos exp(p)) / (n_pos*n_neg)
//       row_loss[i] = (mse_i + LAMBDA * set_i) / BATCH
// ---------------------------------------------------------------------------
__global__ __launch_bounds__(256) void fused_row_kernel(
    const float* __restrict__ pred,
    const int* __restrict__ target,
    const float* __restrict__ weights,
    float* __restrict__ row_loss) {
  const int row = blockIdx.x;
  const size_t base = (size_t)row * VOCAB;
  const f4* p = reinterpret_cast<const f4*>(pred + base);

  __shared__ float s_ss[4], s_es[4];
  __shared__ int tg[SETSZ];

  // stage targets early (wave 0)
  int my = 0;
  if (threadIdx.x < SETSZ) {
    my = target[row * SETSZ + threadIdx.x];
    tg[threadIdx.x] = my;
  }

  // ---- Phase 1: streaming reduction, 2x unrolled nontemporal loads ----
  float ss = 0.f, es = 0.f;
  int j = threadIdx.x;
  for (; j < (VOCAB / 4) - 256; j += 512) {
    f4 a = __builtin_nontemporal_load(p + j);
    f4 b = __builtin_nontemporal_load(p + j + 256);
    ss += a[0] * a[0] + a[1] * a[1] + a[2] * a[2] + a[3] * a[3];
    es += __expf(a[0]) + __expf(a[1]) + __expf(a[2]) + __expf(a[3]);
    ss += b[0] * b[0] + b[1] * b[1] + b[2] * b[2] + b[3] * b[3];
    es += __expf(b[0]) + __expf(b[1]) + __expf(b[2]) + __expf(b[3]);
  }
  if (j < VOCAB / 4) {
    f4 a = __builtin_nontemporal_load(p + j);
    ss += a[0] * a[0] + a[1] * a[1] + a[2] * a[2] + a[3] * a[3];
    es += __expf(a[0]) + __expf(a[1]) + __expf(a[2]) + __expf(a[3]);
  }

  #pragma unroll
  for (int off = 32; off > 0; off >>= 1) {
    ss += __shfl_down(ss, off, 64);
    es += __shfl_down(es, off, 64);
  }
  const int wave = threadIdx.x >> 6;
  const int lane = threadIdx.x & 63;
  if (lane == 0) { s_ss[wave] = ss; s_es[wave] = es; }
  __syncthreads();

  // ---- Phase 2: target handling on wave 0 ----
  if (threadIdx.x < SETSZ) {
    // first-occurrence dedupe
    bool keep = true;
    for (int k = 0; k < threadIdx.x; ++k) {
      if (tg[k] == my) { keep = false; break; }
    }

    float c_mse = 0.f, c_pos = 0.f, c_exp = 0.f, cnt = 0.f;
    if (keep) {
      const float pv = pred[base + my];
      c_mse = 1.f - 2.f * pv;   // (p-1)^2 - p^2
      c_pos = __expf(-pv);
      c_exp = __expf(pv);
      cnt = 1.f;
    }

    #pragma unroll
    for (int off = 32; off > 0; off >>= 1) {
      c_mse += __shfl_down(c_mse, off, 64);
      c_pos += __shfl_down(c_pos, off, 64);
      c_exp += __shfl_down(c_exp, off, 64);
      cnt   += __shfl_down(cnt,   off, 64);
    }

    if (threadIdx.x == 0) {
      const float sumsq  = s_ss[0] + s_ss[1] + s_ss[2] + s_ss[3];
      const float expsum = s_es[0] + s_es[1] + s_es[2] + s_es[3];
      const float n_pos = cnt;
      const float n_neg = (float)VOCAB - n_pos;
      const float mse   = weights[row] * (sumsq + c_mse);
      const float setl  = c_pos * (expsum - c_exp) / (n_pos * n_neg);
      row_loss[row] = (mse + LAMBDA_REG * setl) * (1.0f / (float)BATCH);
    }
  }
}

// ---------------------------------------------------------------------------
// Final deterministic reduction of 4096 row losses -> d_out[0].
// Single block, fixed tree order -> bit-identical across replays.
// ---------------------------------------------------------------------------
__global__ __launch_bounds__(256) void final_reduce_kernel(
    const float* __restrict__ row_loss,
    float* __restrict__ out) {
  float s = 0.f;
  for (int j = threadIdx.x; j < BATCH; j += 256) s += row_loss[j];

  #pragma unroll
  for (int off = 32; off > 0; off >>= 1) s += __shfl_down(s, off, 64);

  __shared__ float sm[4];
  const int wave = threadIdx.x >> 6;
  const int lane = threadIdx.x & 63;
  if (lane == 0) sm[wave] = s;
  __syncthreads();
  if (threadIdx.x == 0) out[0] = sm[0] + sm[1] + sm[2] + sm[3];
}

extern "C" void kernel_launch(void* const* d_in, const int* in_sizes, int n_in,
                              void* d_out, int out_size, void* d_ws, size_t ws_size,
                              hipStream_t stream) {
  const float* pred    = (const float*)d_in[0];
  const int*   target  = (const int*)d_in[1];
  const float* weights = (const float*)d_in[2];
  float* out = (float*)d_out;

  float* row_loss = (float*)d_ws;  // BATCH floats

  fused_row_kernel<<<BATCH, 256, 0, stream>>>(pred, target, weights, row_loss);
  final_reduce_kernel<<<1, 256, 0, stream>>>(row_loss, out);
}